// Round 1
// baseline (132.495 us; speedup 1.0000x reference)
//
#include <hip/hip_runtime.h>

// Global filter: out = irfft2( rfft2(x_grid) * W ), ortho norm, grid 16x16, C=768, B=256.
// Per (b, c): out[n] = (1/256) sum_{k full} Re[ W_full[k] * Xhat[k] * e^{+2pi i k.n/16} ]
// with W_full[k1,k2] = W[k1,k2] (k2<=8), conj(W[(16-k1)%16, 16-k2]) (k2>8).

#define GRID16 16
#define WF 9
#define DIM 768
#define NB 256
#define CT 16           // channels per block
#define NCT (DIM / CT)  // 48

__device__ __forceinline__ void fft16_core(float* xr, float* xi, const float sgn) {
  // bit-reversal for 16
#define SWP(a, b) { float t_ = xr[a]; xr[a] = xr[b]; xr[b] = t_; t_ = xi[a]; xi[a] = xi[b]; xi[b] = t_; }
  SWP(1, 8) SWP(2, 4) SWP(3, 12) SWP(5, 10) SWP(7, 14) SWP(11, 13)
#undef SWP
  const float C16[8] = {1.f, 0.92387953251128674f, 0.70710678118654752f, 0.38268343236508978f,
                        0.f, -0.38268343236508978f, -0.70710678118654752f, -0.92387953251128674f};
  const float S16[8] = {0.f, 0.38268343236508978f, 0.70710678118654752f, 0.92387953251128674f,
                        1.f, 0.92387953251128674f, 0.70710678118654752f, 0.38268343236508978f};
#pragma unroll
  for (int len = 2; len <= 16; len <<= 1) {
#pragma unroll
    for (int start = 0; start < 16; start += len) {
#pragma unroll
      for (int j = 0; j < (len >> 1); j++) {
        const int tw = j * (16 / len);
        const float wr = C16[tw];
        const float wi = sgn * S16[tw];
        const int a = start + j;
        const int b = a + (len >> 1);
        const float br = xr[b], bi = xi[b];
        const float tr = wr * br - wi * bi;
        const float ti = wr * bi + wi * br;
        xr[b] = xr[a] - tr; xi[b] = xi[a] - ti;
        xr[a] += tr;        xi[a] += ti;
      }
    }
  }
}

// Padded LDS stride: index [k][j][c'] -> k*272 + j*16 + c'  (272 = 16*17, makes all
// stage accesses <=2-way bank aliased which is free on CDNA4)
#define KSTR 272
#define LDSZ (15 * KSTR + 15 * 16 + 15 + 1)

__global__ __launch_bounds__(256) void gf_kernel(const float* __restrict__ x,
                                                 const float* __restrict__ w,
                                                 float* __restrict__ out) {
  __shared__ float xs[256 * CT];   // [token][c']  16KB
  __shared__ float Ar[LDSZ];       // U then reused as Q (re)
  __shared__ float Ai[LDSZ];       // U then reused as Q (im)

  const int blk = blockIdx.x;
  const int ct = blk >> 8;          // 0..47  (ct-outer => W slice stays hot in L2)
  const int b = blk & 255;          // 0..255
  const int c0 = ct * CT;
  const int t = threadIdx.x;

  const float* xb = x + (size_t)b * (256 * DIM) + c0;

  // ---- stage 0: coalesced load of x[b, :, :, c0:c0+16] into LDS ----
#pragma unroll
  for (int ii = 0; ii < 16; ii++) {
    const int e = ii * 256 + t;          // 0..4095
    const int token = e >> 4;
    const int cc = e & 15;
    xs[e] = xb[token * DIM + cc];
  }
  __syncthreads();

  const int r = t >> 4;    // row index role (j / k1 / n2 depending on stage)
  const int cc = t & 15;   // channel within tile

  // ---- stage 1: forward FFT along i (axis 1), thread = (j, c') ----
  {
    float vr[16], vi[16];
#pragma unroll
    for (int i = 0; i < 16; i++) {
      vr[i] = xs[(i * 16 + r) * 16 + cc];
      vi[i] = 0.f;
    }
    fft16_core(vr, vi, -1.f);
#pragma unroll
    for (int k = 0; k < 16; k++) {
      Ar[k * KSTR + r * 16 + cc] = vr[k];
      Ai[k * KSTR + r * 16 + cc] = vi[k];
    }
  }
  __syncthreads();

  // ---- stages 2-4 fused: thread = (k1, c') ----
  {
    float vr[16], vi[16];
#pragma unroll
    for (int j = 0; j < 16; j++) {
      vr[j] = Ar[r * KSTR + j * 16 + cc];
      vi[j] = Ai[r * KSTR + j * 16 + cc];
    }
    __syncthreads();   // everyone done reading U before Q overwrite

    fft16_core(vr, vi, -1.f);   // vr/vi = Xhat[k1, k2], k2 = 0..15

    // multiply by W_full[k1, k2, c] / 256
    const int k1 = r;
    const float* wrow  = w + ((size_t)(k1 * WF) * DIM + (c0 + cc)) * 2;
    const float* wmrow = w + ((size_t)(((16 - k1) & 15) * WF) * DIM + (c0 + cc)) * 2;
    const float nrm = 1.f / 256.f;
#pragma unroll
    for (int k2 = 0; k2 < 16; k2++) {
      float wr_, wi_;
      if (k2 <= 8) {
        wr_ = wrow[(size_t)k2 * DIM * 2];
        wi_ = wrow[(size_t)k2 * DIM * 2 + 1];
      } else {
        wr_ =  wmrow[(size_t)(16 - k2) * DIM * 2];
        wi_ = -wmrow[(size_t)(16 - k2) * DIM * 2 + 1];
      }
      wr_ *= nrm; wi_ *= nrm;
      const float pr = vr[k2] * wr_ - vi[k2] * wi_;
      const float pi = vr[k2] * wi_ + vi[k2] * wr_;
      vr[k2] = pr; vi[k2] = pi;
    }

    fft16_core(vr, vi, 1.f);    // inverse along k2 -> n2 axis (unnormalized)

#pragma unroll
    for (int n2 = 0; n2 < 16; n2++) {
      Ar[r * KSTR + n2 * 16 + cc] = vr[n2];
      Ai[r * KSTR + n2 * 16 + cc] = vi[n2];
    }
  }
  __syncthreads();

  // ---- stage 5: inverse FFT along k1 -> n1, take real, store. thread = (n2, c') ----
  {
    float vr[16], vi[16];
#pragma unroll
    for (int k1 = 0; k1 < 16; k1++) {
      vr[k1] = Ar[k1 * KSTR + r * 16 + cc];
      vi[k1] = Ai[k1 * KSTR + r * 16 + cc];
    }
    fft16_core(vr, vi, 1.f);

    float* ob = out + (size_t)b * (256 * DIM) + c0;
#pragma unroll
    for (int n1 = 0; n1 < 16; n1++) {
      ob[(n1 * 16 + r) * DIM + cc] = vr[n1];
    }
  }
}

extern "C" void kernel_launch(void* const* d_in, const int* in_sizes, int n_in,
                              void* d_out, int out_size, void* d_ws, size_t ws_size,
                              hipStream_t stream) {
  const float* x = (const float*)d_in[0];
  const float* w = (const float*)d_in[1];
  float* out = (float*)d_out;
  dim3 grid(NCT * NB);   // 48 * 256 = 12288, channel-tile outer
  dim3 block(256);
  hipLaunchKernelGGL(gf_kernel, grid, block, 0, stream, x, w, out);
}

// Round 2
// 102.465 us; speedup vs baseline: 1.2931x; 1.2931x over previous
//
#include <hip/hip_runtime.h>

// out = irfft2( rfft2(x_grid) * W ), ortho, grid 16x16, C=768, B=256.
// Pipeline per block (b, 32 channels), 256 threads:
//  S1: per (i, ch-pair): pack 2 channels as complex, fft16 over j, unpack to
//      half-spectra k2=0..8 (k2 in {0,8} real, packed into slot 0). LDS U.
//  S2: per (k2-slot, ch): fft16 over i, weight multiply (norm folded), ifft16
//      over k1 -> n1. Slot 0 handles k2=0&8 together via folded weights,
//      storing only Re (irfft drops imag of cols 0,8). LDS Q (aliases U).
//  S3: per (n1, ch-pair): build Hermitian-extended column spectra for 2
//      channels packed as one complex ifft16 over k2 -> n2, store real pair.

#define DIM 768
#define CT 32
#define NCT (DIM / CT)   // 24
#define NB 256
#define IP 258           // float2 pitch per i-row: 8 slots * 32 ch + 2 pad

#define R2c  0.70710678118654752f
#define C1c  0.92387953251128674f
#define S1cc 0.38268343236508978f
#define INV512  (1.f / 512.f)
#define INV256  (1.f / 256.f)
#define INV1024 (1.f / 1024.f)

template <int SGN>   // SGN = -1 forward, +1 inverse (unnormalized)
__device__ __forceinline__ void fft16(float* xr, float* xi) {
#define SWP(a, b) { float t_ = xr[a]; xr[a] = xr[b]; xr[b] = t_; t_ = xi[a]; xi[a] = xi[b]; xi[b] = t_; }
  SWP(1, 8) SWP(2, 4) SWP(3, 12) SWP(5, 10) SWP(7, 14) SWP(11, 13)
#undef SWP
#define BF1(a, b) { float tr = xr[b], ti = xi[b]; xr[b] = xr[a] - tr; xi[b] = xi[a] - ti; xr[a] += tr; xi[a] += ti; }
#define BFI(a, b) { float tr, ti; if (SGN < 0) { tr = xi[b]; ti = -xr[b]; } else { tr = -xi[b]; ti = xr[b]; } \
                    xr[b] = xr[a] - tr; xi[b] = xi[a] - ti; xr[a] += tr; xi[a] += ti; }
#define BFW(a, b, Wr, Wi) { float tr = (Wr) * xr[b] - (Wi) * xi[b], ti = (Wr) * xi[b] + (Wi) * xr[b]; \
                            xr[b] = xr[a] - tr; xi[b] = xi[a] - ti; xr[a] += tr; xi[a] += ti; }
  // stage len=2
  BF1(0, 1) BF1(2, 3) BF1(4, 5) BF1(6, 7) BF1(8, 9) BF1(10, 11) BF1(12, 13) BF1(14, 15)
  // stage len=4
  BF1(0, 2) BF1(4, 6) BF1(8, 10) BF1(12, 14)
  BFI(1, 3) BFI(5, 7) BFI(9, 11) BFI(13, 15)
  // stage len=8
  BF1(0, 4) BF1(8, 12)
  BFW(1, 5, R2c, SGN * R2c) BFW(9, 13, R2c, SGN * R2c)
  BFI(2, 6) BFI(10, 14)
  BFW(3, 7, -R2c, SGN * R2c) BFW(11, 15, -R2c, SGN * R2c)
  // stage len=16
  BF1(0, 8)
  BFW(1, 9, C1c, SGN * S1cc)
  BFW(2, 10, R2c, SGN * R2c)
  BFW(3, 11, S1cc, SGN * C1c)
  BFI(4, 12)
  BFW(5, 13, -S1cc, SGN * C1c)
  BFW(6, 14, -R2c, SGN * R2c)
  BFW(7, 15, -C1c, SGN * S1cc)
#undef BF1
#undef BFI
#undef BFW
}

__global__ __launch_bounds__(256, 4) void gf2_kernel(const float* __restrict__ x,
                                                     const float* __restrict__ w,
                                                     float* __restrict__ out) {
  __shared__ __align__(16) float2 E[16 * IP];   // 33 KB, U then aliased as Q
  float4* E4 = (float4*)E;

  const int blk = blockIdx.x;
  const int ct = blk >> 8;        // 0..23  (ct-outer: W slice L2-hot across 256 blocks)
  const int b  = blk & 255;
  const int c0 = ct * CT;
  const int t  = threadIdx.x;
  const int r  = t >> 4;          // i (S1) / n1 (S3)
  const int p  = t & 15;          // channel-pair index

  // ---------------- S1: rfft over j, 2 channels packed ----------------
  {
    const float2* xp = (const float2*)(x + (size_t)b * 196608 + (size_t)r * 12288 + c0) + p;
    float zr[16], zi[16];
#pragma unroll
    for (int j = 0; j < 16; j++) { float2 v = xp[j * 384]; zr[j] = v.x; zi[j] = v.y; }
    fft16<-1>(zr, zi);
    // slot 0: (F[i][0], F[i][8]) for both channels (1x scale)
    E4[r * 129 + p] = make_float4(zr[0], zr[8], zi[0], zi[8]);
    // slots k=1..7: doubled half-spectra A'=2*F_a, B'=2*F_b
#pragma unroll
    for (int k = 1; k <= 7; k++) {
      const int m = 16 - k;
      float Ar = zr[k] + zr[m], Ai = zi[k] - zi[m];
      float Br = zi[k] + zi[m], Bi = zr[m] - zr[k];
      E4[r * 129 + k * 16 + p] = make_float4(Ar, Ai, Br, Bi);
    }
  }
  __syncthreads();

  // ---------------- S2: fft over i, weight, ifft over k1 ----------------
  {
    const int s = t >> 5;         // slot 0..7
    const int c = t & 31;         // channel within tile
    float gr[16], gi[16];
    const float2* col = E + s * 32 + c;
#pragma unroll
    for (int i = 0; i < 16; i++) { float2 v = col[i * IP]; gr[i] = v.x; gi[i] = v.y; }
    __syncthreads();              // all reads of U done before Q overwrites

    if (s == 0) {
      // packed task: columns k2=0 and k2=8 (real), folded weights
      fft16<-1>(gr, gi);
      const float* wc = w + (size_t)(c0 + c) * 2;   // stride per k1: 13824 floats; +12288 for k2=8
      {
        float2 a0 = *(const float2*)(wc);
        float2 a8 = *(const float2*)(wc + 12288);
        float2 b0 = *(const float2*)(wc + 8 * 13824);
        float2 b8 = *(const float2*)(wc + 8 * 13824 + 12288);
        gr[0] = gr[0] * (a0.x * INV256);
        gi[0] = gi[0] * (a8.x * INV256);
        gr[8] = gr[8] * (b0.x * INV256);
        gi[8] = gi[8] * (b8.x * INV256);
      }
#pragma unroll
      for (int k = 1; k <= 7; k++) {
        const int m = 16 - k;
        float2 a0 = *(const float2*)(wc + (size_t)k * 13824);
        float2 m0 = *(const float2*)(wc + (size_t)m * 13824);
        float2 a8 = *(const float2*)(wc + (size_t)k * 13824 + 12288);
        float2 m8 = *(const float2*)(wc + (size_t)m * 13824 + 12288);
        float Vpr = (a0.x + m0.x + a8.x + m8.x) * INV1024;
        float Vpi = (a0.y - m0.y + a8.y - m8.y) * INV1024;
        float Vmr = (a0.x + m0.x - a8.x - m8.x) * INV1024;
        float Vmi = (a0.y - m0.y - a8.y + m8.y) * INV1024;
        float ur = gr[k], ui = gi[k], vr = gr[m], vi = gi[m];
        float nkr = ur * Vpr - ui * Vpi + vr * Vmr + vi * Vmi;
        float nki = ur * Vpi + ui * Vpr + vr * Vmi - vi * Vmr;
        float nmr = vr * Vpr + vi * Vpi + ur * Vmr - ui * Vmi;
        float nmi = vi * Vpr - vr * Vpi - ur * Vmi - ui * Vmr;
        gr[k] = nkr; gi[k] = nki; gr[m] = nmr; gi[m] = nmi;
      }
      fft16<1>(gr, gi);           // (re, im) = (Re Q[.][0], Re Q[.][8]) -- both real
    } else {
      // regular task: column k2 = s (stored doubled -> weight * 1/512)
      float wvr[16], wvi[16];
      const float* wp = w + (size_t)(s * 768 + c0 + c) * 2;
#pragma unroll
      for (int k1 = 0; k1 < 16; k1++) {
        float2 wv = *(const float2*)(wp + (size_t)k1 * 13824);
        wvr[k1] = wv.x * INV512; wvi[k1] = wv.y * INV512;
      }
      fft16<-1>(gr, gi);
#pragma unroll
      for (int k1 = 0; k1 < 16; k1++) {
        float yr = gr[k1] * wvr[k1] - gi[k1] * wvi[k1];
        float yi = gr[k1] * wvi[k1] + gi[k1] * wvr[k1];
        gr[k1] = yr; gi[k1] = yi;
      }
      fft16<1>(gr, gi);
    }

    float2* colo = E + s * 32 + c;
#pragma unroll
    for (int n1 = 0; n1 < 16; n1++) { colo[n1 * IP] = make_float2(gr[n1], gi[n1]); }
  }
  __syncthreads();

  // ---------------- S3: irfft over k2, 2 channels packed, store ----------------
  {
    float hr[16], hi[16];
#pragma unroll
    for (int k = 0; k <= 7; k++) {
      float4 v = E4[r * 129 + k * 16 + p];   // {a.re, a.im, b.re, b.im} (k>0) / {R0a,R8a,R0b,R8b} (k=0)
      if (k == 0) {
        hr[0] = v.x; hi[0] = v.z;   // H[0] = (R0_a, R0_b)
        hr[8] = v.y; hi[8] = v.w;   // H[8] = (R8_a, R8_b)
      } else {
        // h[k] = Qa[k] + i*Qb[k]; h[16-k] = conj(Qa[k]) + i*conj(Qb[k])
        hr[k] = v.x - v.w;      hi[k] = v.y + v.z;
        hr[16 - k] = v.x + v.w; hi[16 - k] = v.z - v.y;
      }
    }
    fft16<1>(hr, hi);   // (re, im) = (out_a[n2], out_b[n2])
    float2* op = (float2*)(out + (size_t)b * 196608 + (size_t)r * 12288 + c0) + p;
#pragma unroll
    for (int n2 = 0; n2 < 16; n2++) { op[n2 * 384] = make_float2(hr[n2], hi[n2]); }
  }
}

extern "C" void kernel_launch(void* const* d_in, const int* in_sizes, int n_in,
                              void* d_out, int out_size, void* d_ws, size_t ws_size,
                              hipStream_t stream) {
  const float* x = (const float*)d_in[0];
  const float* w = (const float*)d_in[1];
  float* out = (float*)d_out;
  dim3 grid(NCT * NB);   // 24 * 256 = 6144
  dim3 block(256);
  hipLaunchKernelGGL(gf2_kernel, grid, block, 0, stream, x, w, out);
}